// Round 6
// baseline (200.331 us; speedup 1.0000x reference)
//
#include <hip/hip_runtime.h>

// Forward kinematics, H36M 17-joint skeleton. One thread = one sample.
// R9: input staging via __builtin_amdgcn_global_load_lds (async DMA).
// Why: R3..R8 invariant = ~71us, ~2.4TB/s effective, VALU 12%, wave lifetime
// ~42k cy vs 2.6k cy of work. At VGPR=68 the allocator sinks the 16 input
// loads just-in-time (R8 proved a bigger budget doesn't change its choice),
// so each wave serializes ~16 queued-latency exposures (~2.5k cy each = the
// whole lifetime). DMA takes the register allocator out of the loop: 13
// in-flight asynchronous 1KB transfers per wave, zero VGPRs, one vmcnt(0).
// Source addresses are per-lane (m173 pattern): slot m=j*64+lane maps to
// (sample s=m/13, chunk c=m%13), c==12 is a discarded duplicate -> the DMA
// stream is the block's contiguous 12KB (line-coalesced), while LDS lands as
// 52-word (13-float4) per-sample regions = free padding (8-way banks, ~2.9x
// on b32 reads, ~400cy/wave -- cheap).
// The SAME 52-word region is reused in place for output staging: joint j
// overwrites words 3j..3j+2 only after bone j's input words were consumed
// (read-one-bone-ahead interleave below). Total LDS = 64*52*4 = 13312 B ->
// 12 blocks/CU = 12 waves/CU, full async input, coalesced drain.
// blen stays as 4 direct float4 loads issued under the same vmcnt umbrella.

#define NB 64

#define GLB_PTR(x) ((const __attribute__((address_space(1))) void*)(x))
#define LDS_PTR(x) ((__attribute__((address_space(3))) void*)(x))

__device__ __forceinline__ void mm3(const float A[9], const float B[9], float C[9]) {
#pragma unroll
    for (int r = 0; r < 3; ++r) {
        C[3*r+0] = A[3*r+0]*B[0] + A[3*r+1]*B[3] + A[3*r+2]*B[6];
        C[3*r+1] = A[3*r+0]*B[1] + A[3*r+1]*B[4] + A[3*r+2]*B[7];
        C[3*r+2] = A[3*r+0]*B[2] + A[3*r+1]*B[5] + A[3*r+2]*B[8];
    }
}

// R = Rx(a) @ Ry(b) @ Rz(c)  (pytorch3d euler_angles_to_matrix 'XYZ'), row-major
__device__ __forceinline__ void erot(float a, float b, float c, float R[9]) {
    float sx, cx, sy, cy, sz, cz;
    __sincosf(a, &sx, &cx);
    __sincosf(b, &sy, &cy);
    __sincosf(c, &sz, &cz);
    R[0] = cy*cz;             R[1] = -cy*sz;            R[2] = sy;
    R[3] = sx*sy*cz + cx*sz;  R[4] = -sx*sy*sz + cx*cz; R[5] = -sx*cy;
    R[6] = -cx*sy*cz + sx*sz; R[7] = cx*sy*sz + sx*cz;  R[8] = cx*cy;
}

__global__ void __launch_bounds__(NB, 3)
fk17_kernel(const float* __restrict__ euler, const float* __restrict__ blen,
            float* __restrict__ out, int n)
{
    __shared__ float s_b[NB * 52];   // 13312 B: per-thread 52-word region

    const int tid    = threadIdx.x;
    const int block0 = blockIdx.x * NB;
    const int nvalid = min(NB, n - block0);
    const int t      = block0 + tid;
    const int tc     = min(t, n - 1);

    // ---- async DMA: euler block -> LDS, 13 instrs, line-coalesced source.
    // LDS dest is linear (base + lane*16); slot m = j*64+tid.
    // s = m/13 (sample in block), c = m%13 (float4 chunk); c==12 = pad slot,
    // filled with a duplicate of chunk 0 (in-bounds, L1-hot, discarded).
#pragma unroll
    for (int j = 0; j < 13; ++j) {
        int m = j * 64 + tid;
        int s = m / 13;                  // const-div -> magic mul
        int c = m - s * 13;
        if (c == 12) c = 0;              // pad slot: harmless duplicate
        int gs = min(block0 + s, n - 1); // clamp for the partial last block
        __builtin_amdgcn_global_load_lds(
            GLB_PTR(euler + (size_t)gs * 48 + c * 4),
            LDS_PTR(s_b + j * 256), 16, 0, 0);
    }

    // ---- blen: 4 direct float4 loads, in flight alongside the DMA ----
    float L[16];
    {
        const float4* gb4 = (const float4*)(blen + (size_t)tc * 16);
#pragma unroll
        for (int q = 0; q < 4; ++q) {
            float4 v = gb4[q];
            L[4*q+0] = v.x; L[4*q+1] = v.y; L[4*q+2] = v.z; L[4*q+3] = v.w;
        }
    }

    asm volatile("s_waitcnt vmcnt(0)" ::: "memory");  // DMA + blen complete
    __syncthreads();                                   // 1 wave: formality

    if (tid < nvalid) {
        // o = this sample's 52-word LDS region. Inputs live at words 3i..3i+2
        // (bone i); outputs overwrite words 3j..3j+2 (joint j). Discipline:
        // read bone i's triple into regs (e/f alternating, one bone ahead)
        // BEFORE writing joint i to the same words. Same-address LDS ops are
        // order-preserved by the compiler; distinct-offset ops may reorder
        // freely (no hazard).
        float* o = s_b + tid * 52;
        float ex, ey, ez, fx, fy, fz;
        float Ma[9], Mb[9], M8[9], R[9];
        float px, py, pz, p8x, p8y, p8z;

        ex = o[0];  ey = o[1];  ez = o[2];    // bone 0
        fx = o[3];  fy = o[4];  fz = o[5];    // bone 1
        o[0] = 0.f; o[1] = 0.f; o[2] = 0.f;   // root (bone 0 consumed)

        // chain 0 -> 1 -> 2 -> 3 (bones 0,1,2)
        erot(ex, ey, ez, Ma);                               // M1
        px = L[0]*Ma[6]; py = L[0]*Ma[7]; pz = L[0]*Ma[8];
        ex = o[6];  ey = o[7];  ez = o[8];    // bone 2
        o[3] = px; o[4] = py; o[5] = pz;      // joint 1 (bone 1 read)
        erot(fx, fy, fz, R); mm3(Ma, R, Mb);                // M2
        px += L[1]*Mb[6]; py += L[1]*Mb[7]; pz += L[1]*Mb[8];
        fx = o[9];  fy = o[10]; fz = o[11];   // bone 3
        o[6] = px; o[7] = py; o[8] = pz;      // joint 2 (bone 2 read)
        erot(ex, ey, ez, R); mm3(Mb, R, Ma);                // M3
        px += L[2]*Ma[6]; py += L[2]*Ma[7]; pz += L[2]*Ma[8];
        ex = o[12]; ey = o[13]; ez = o[14];   // bone 4
        o[9] = px; o[10] = py; o[11] = pz;    // joint 3 (bone 3 read)

        // chain 0 -> 4 -> 5 -> 6 (bones 3,4,5)
        erot(fx, fy, fz, Ma);                               // M4
        px = L[3]*Ma[6]; py = L[3]*Ma[7]; pz = L[3]*Ma[8];
        fx = o[15]; fy = o[16]; fz = o[17];   // bone 5
        o[12] = px; o[13] = py; o[14] = pz;   // joint 4 (bone 4 read)
        erot(ex, ey, ez, R); mm3(Ma, R, Mb);                // M5
        px += L[4]*Mb[6]; py += L[4]*Mb[7]; pz += L[4]*Mb[8];
        ex = o[18]; ey = o[19]; ez = o[20];   // bone 6
        o[15] = px; o[16] = py; o[17] = pz;   // joint 5 (bone 5 read)
        erot(fx, fy, fz, R); mm3(Mb, R, Ma);                // M6
        px += L[5]*Ma[6]; py += L[5]*Ma[7]; pz += L[5]*Ma[8];
        fx = o[21]; fy = o[22]; fz = o[23];   // bone 7
        o[18] = px; o[19] = py; o[20] = pz;   // joint 6 (bone 6 read)

        // spine 0 -> 7 -> 8 (bones 6,7)
        erot(ex, ey, ez, Ma);                               // M7
        px = L[6]*Ma[6]; py = L[6]*Ma[7]; pz = L[6]*Ma[8];
        ex = o[24]; ey = o[25]; ez = o[26];   // bone 8
        o[21] = px; o[22] = py; o[23] = pz;   // joint 7 (bone 7 read)
        erot(fx, fy, fz, R); mm3(Ma, R, M8);                // M8
        px += L[7]*M8[6]; py += L[7]*M8[7]; pz += L[7]*M8[8];
        fx = o[27]; fy = o[28]; fz = o[29];   // bone 9
        o[24] = px; o[25] = py; o[26] = pz;   // joint 8 (bone 8 read)
        p8x = px; p8y = py; p8z = pz;

        // branch 8 -> 9 -> 10 (bones 8,9)
        erot(ex, ey, ez, R); mm3(M8, R, Ma);
        px = p8x + L[8]*Ma[6]; py = p8y + L[8]*Ma[7]; pz = p8z + L[8]*Ma[8];
        ex = o[30]; ey = o[31]; ez = o[32];   // bone 10
        o[27] = px; o[28] = py; o[29] = pz;   // joint 9 (bone 9 read)
        erot(fx, fy, fz, R); mm3(Ma, R, Mb);
        px += L[9]*Mb[6]; py += L[9]*Mb[7]; pz += L[9]*Mb[8];
        fx = o[33]; fy = o[34]; fz = o[35];   // bone 11
        o[30] = px; o[31] = py; o[32] = pz;   // joint 10 (bone 10 read)

        // branch 8 -> 11 -> 12 -> 13 (bones 10,11,12)
        erot(ex, ey, ez, R); mm3(M8, R, Ma);
        px = p8x + L[10]*Ma[6]; py = p8y + L[10]*Ma[7]; pz = p8z + L[10]*Ma[8];
        ex = o[36]; ey = o[37]; ez = o[38];   // bone 12
        o[33] = px; o[34] = py; o[35] = pz;   // joint 11 (bone 11 read)
        erot(fx, fy, fz, R); mm3(Ma, R, Mb);
        px += L[11]*Mb[6]; py += L[11]*Mb[7]; pz += L[11]*Mb[8];
        fx = o[39]; fy = o[40]; fz = o[41];   // bone 13
        o[36] = px; o[37] = py; o[38] = pz;   // joint 12 (bone 12 read)
        erot(ex, ey, ez, R); mm3(Mb, R, Ma);
        px += L[12]*Ma[6]; py += L[12]*Ma[7]; pz += L[12]*Ma[8];
        ex = o[42]; ey = o[43]; ez = o[44];   // bone 14
        o[39] = px; o[40] = py; o[41] = pz;   // joint 13 (bone 13 read)

        // branch 8 -> 14 -> 15 -> 16 (bones 13,14,15)
        erot(fx, fy, fz, R); mm3(M8, R, Ma);
        px = p8x + L[13]*Ma[6]; py = p8y + L[13]*Ma[7]; pz = p8z + L[13]*Ma[8];
        fx = o[45]; fy = o[46]; fz = o[47];   // bone 15
        o[42] = px; o[43] = py; o[44] = pz;   // joint 14 (bone 14 read)
        erot(ex, ey, ez, R); mm3(Ma, R, Mb);
        px += L[14]*Mb[6]; py += L[14]*Mb[7]; pz += L[14]*Mb[8];
        o[45] = px; o[46] = py; o[47] = pz;   // joint 15 (bone 15 read)
        erot(fx, fy, fz, R); mm3(Mb, R, Ma);
        px += L[15]*Ma[6]; py += L[15]*Ma[7]; pz += L[15]*Ma[8];
        o[48] = px; o[49] = py; o[50] = pz;   // joint 16 (pad words, no hazard)
    }
    __syncthreads();

    // ---- drain: LDS (stride 52) -> global (stride 51), lane-consecutive.
    // flat out idx m: sample s = m/51, LDS word = m + s. Each store instr
    // writes 256 contiguous bytes -> fully coalesced, WRITE_SIZE exact.
    {
        float* og = out + (size_t)block0 * 51;
        if (nvalid == NB) {
#pragma unroll
            for (int k = 0; k < 51; ++k) {
                int m = tid + 64 * k;
                int s = m / 51;              // const-div -> magic mul
                og[m] = s_b[m + s];
            }
        } else {
            const int tot = nvalid * 51;
            for (int m = tid; m < tot; m += NB) {
                int s = m / 51;
                og[m] = s_b[m + s];
            }
        }
    }
}

extern "C" void kernel_launch(void* const* d_in, const int* in_sizes, int n_in,
                              void* d_out, int out_size, void* d_ws, size_t ws_size,
                              hipStream_t stream) {
    const float* euler = (const float*)d_in[0];   // (N,16,3) fp32
    const float* blen  = (const float*)d_in[1];   // (N,16,1) fp32
    float* out = (float*)d_out;                   // (N,17,3) fp32

    const int n    = in_sizes[0] / 48;
    const int grid = (n + NB - 1) / NB;
    fk17_kernel<<<grid, NB, 0, stream>>>(euler, blen, out, n);
}